// Round 22
// baseline (892.359 us; speedup 1.0000x reference)
//
#include <hip/hip_runtime.h>
#include <hip/hip_bf16.h>
#include <stdint.h>

// Problem constants (fixed by the reference).
#define M_DIM 8192
#define K_DIM 2048
#define N_DIM 2048

typedef __attribute__((ext_vector_type(8))) short bf16x8;
typedef __attribute__((ext_vector_type(4))) float f32x4;

// fp32 -> bf16 round-to-nearest-even (data has no NaNs).
__device__ __forceinline__ ushort f2bf(float f) {
    union { float f; uint32_t u; } v; v.f = f;
    uint32_t u = v.u;
    uint32_t r = u + 0x7fffu + ((u >> 16) & 1u);
    return (ushort)(r >> 16);
}

typedef const __attribute__((address_space(1))) uint32_t gu32;
typedef __attribute__((address_space(3))) uint32_t lu32;
__device__ __forceinline__ void load_lds16(const void* g, void* l) {
    __builtin_amdgcn_global_load_lds((gu32*)g, (lu32*)l, 16, 0, 0);
}

// Images (XOR-swizzled LDS format):
//   A: per tile (rb*32+kt), 8KB: byte(r,k2) = r*128 + (k2 ^ ((r&7)<<4))
//   B: per (cb,kt), 8KB panel at Btk + cb*256KB + kt*8KB  ([cb][kt])
//
// SINGLE regular kernel, 1024 blocks, producer/consumer overlap:
//   blocks [0,256): 4 conv units + 8 scan units (k-interleaved: rb 0-15
//     complete first), each unit released via {fence, barrier, atomicAdd}.
//   all blocks: pull gemm tiles (qi -> rb=qi>>5, cb=qi&31) from an atomic
//     queue; spin on convCnt[cb]==32 && scanCnt[rb]==16; acquire fence; gemm.
// Overlap: gemm NT writes run while later scan units still stream A reads.
__global__ __launch_bounds__(256, 4) void fused(const float* __restrict__ A,
                                                const float* __restrict__ B,
                                                char* __restrict__ Btk,
                                                char* __restrict__ Abf,
                                                uint8_t* __restrict__ maskb,
                                                uint32_t* __restrict__ convCnt,
                                                uint32_t* __restrict__ scanCnt,
                                                uint32_t* __restrict__ queue,
                                                float* __restrict__ C) {
    __shared__ __align__(16) char smem[16384];
    __shared__ int sh_g;
    const int b = blockIdx.x;
    const int t = threadIdx.x;

    if (b < 256) {
        // ================= producer: 4 conv units =================
        ushort(*lds)[70] = (ushort(*)[70])smem;
#pragma unroll 1
        for (int j = 0; j < 4; ++j) {
            const int c = j * 256 + b;        // conv unit 0..1023
            const int cbi = c & 31;
            const int kt = c >> 5;
            const int c0 = cbi * 64;
            const int r0 = kt * 64;
            const int r  = t >> 2;
            const int cs = (t & 3) << 2;
            __syncthreads();                  // smem reuse across units
#pragma unroll
            for (int i = 0; i < 4; ++i) {
                int cc = cs + i * 16;
                float4 v = *(const float4*)(B + (size_t)(r0 + r) * N_DIM + c0 + cc);
                lds[r][cc + 0] = f2bf(v.x);
                lds[r][cc + 1] = f2bf(v.y);
                lds[r][cc + 2] = f2bf(v.z);
                lds[r][cc + 3] = f2bf(v.w);
            }
            __syncthreads();
            const int ct = t >> 2;
            const int s  = (t & 3) * 16;
            uint4 tmpv[2];
            ushort* tmp = (ushort*)tmpv;
#pragma unroll
            for (int jj = 0; jj < 16; ++jj) tmp[jj] = lds[s + jj][ct];
            char* dst = Btk + (size_t)cbi * 262144 + (size_t)kt * 8192 + ct * 128;
            const int swn = (ct & 7) << 4;
            *(uint4*)(dst + ((s * 2)      ^ swn)) = tmpv[0];
            *(uint4*)(dst + ((s * 2 + 16) ^ swn)) = tmpv[1];
            __threadfence();                  // release this unit's writes
            __syncthreads();
            if (t == 0) atomicAdd(&convCnt[cbi], 1u);
        }

        // ================= producer: 8 scan units (2 k-tiles each) =========
        // unit u = k*256 + b  (k-round interleave: rb 0-15 finish in round 0)
        const int r  = t >> 2;
        const int cs = (t & 3) << 2;
        const int sw = (r & 7) << 4;
#pragma unroll 1
        for (int k = 0; k < 8; ++k) {
            const int u = k * 256 + b;        // 0..2047
            const int rb = u >> 4;
            const int part = u & 15;
            const int kt0 = part * 2;
            const float* base = A + (size_t)(rb * 64 + r) * K_DIM + kt0 * 64 + cs;
            uint32_t bits = 0;
            float4 cur[4], nxt[4];
#pragma unroll
            for (int i = 0; i < 4; ++i) cur[i] = *(const float4*)(base + i * 16);
#pragma unroll
            for (int it = 0; it < 2; ++it) {
                if (it < 1) {
#pragma unroll
                    for (int i = 0; i < 4; ++i)
                        nxt[i] = *(const float4*)(base + 64 + i * 16);
                }
                bool nz = false;
#pragma unroll
                for (int i = 0; i < 4; ++i)
                    nz = nz || (cur[i].x != 0.f) || (cur[i].y != 0.f) ||
                               (cur[i].z != 0.f) || (cur[i].w != 0.f);
                int anynz = __syncthreads_or((int)nz);
                if (anynz) {
                    bits |= 1u << it;
                    char* dst = Abf + (size_t)(rb * 32 + kt0 + it) * 8192 + r * 128;
#pragma unroll
                    for (int i = 0; i < 4; ++i) {
                        uint32_t lo = (uint32_t)f2bf(cur[i].x) | ((uint32_t)f2bf(cur[i].y) << 16);
                        uint32_t hi = (uint32_t)f2bf(cur[i].z) | ((uint32_t)f2bf(cur[i].w) << 16);
                        *(uint2*)(dst + ((cs * 2 + i * 32) ^ sw)) = make_uint2(lo, hi);
                    }
                }
#pragma unroll
                for (int i = 0; i < 4; ++i) cur[i] = nxt[i];
            }
            if (t == 0) maskb[u] = (uint8_t)bits;   // u == rb*16 + part
            __threadfence();                  // release Abf + mask
            __syncthreads();
            if (t == 0) atomicAdd(&scanCnt[rb], 1u);
        }
    }

    // ================= consumer: gemm via atomic work queue =================
    char* sA = smem;
    char* sB = smem + 8192;
    const int lane = t & 63;
    const int wid = t >> 6;
    const int wm = wid >> 1;
    const int wn = wid & 1;

    for (;;) {
        if (t == 0) sh_g = (int)atomicAdd(queue, 1u);
        __syncthreads();
        const int g = sh_g;
        if (g >= 4096) break;
        const int rb = g >> 5;               // rb-ascending: matches scan order
        const int cb = g & 31;               // 32 consecutive tiles share A row

        if (t == 0) {
            while (atomicAdd(&convCnt[cb], 0u) < 32u) __builtin_amdgcn_s_sleep(16);
            while (atomicAdd(&scanCnt[rb], 0u) < 16u) __builtin_amdgcn_s_sleep(16);
        }
        __syncthreads();
        __threadfence();                      // acquire producer data

        uint32_t m = 0;
        const uint8_t* mbp = maskb + rb * 16;
#pragma unroll
        for (int u2 = 0; u2 < 16; ++u2) m |= ((uint32_t)mbp[u2]) << (2 * u2);

        f32x4 acc[2][2];
#pragma unroll
        for (int i = 0; i < 2; ++i)
#pragma unroll
            for (int j = 0; j < 2; ++j) acc[i][j] = (f32x4){0.f, 0.f, 0.f, 0.f};

        const char* bcol = Btk + (size_t)cb * 262144;

        while (m) {
            const int kt = __ffs((int)m) - 1;
            m &= (m - 1);
            {
                const char* bt = bcol + (size_t)kt * 8192;
#pragma unroll
                for (int i = 0; i < 2; ++i) {
                    const int ch = wid * 2 + i;
                    load_lds16(bt + ch * 1024 + lane * 16, sB + ch * 1024);
                }
                const char* at = Abf + (size_t)(rb * 32 + kt) * 8192;
#pragma unroll
                for (int i = 0; i < 2; ++i) {
                    const int ch = wid * 2 + i;
                    load_lds16(at + ch * 1024 + lane * 16, sA + ch * 1024);
                }
            }
            __syncthreads();

#pragma unroll
            for (int ks = 0; ks < 2; ++ks) {
                bf16x8 af[2], bfr[2];
#pragma unroll
                for (int mf = 0; mf < 2; ++mf) {
                    int row = wm * 32 + mf * 16 + (lane & 15);
                    int byte = row * 128 + (ks * 32 + (lane >> 4) * 8) * 2;
                    byte ^= ((row & 7) << 4);
                    af[mf] = *(const bf16x8*)(sA + byte);
                }
#pragma unroll
                for (int nf = 0; nf < 2; ++nf) {
                    int row = wn * 32 + nf * 16 + (lane & 15);
                    int byte = row * 128 + (ks * 32 + (lane >> 4) * 8) * 2;
                    byte ^= ((row & 7) << 4);
                    bfr[nf] = *(const bf16x8*)(sB + byte);
                }
#pragma unroll
                for (int mf = 0; mf < 2; ++mf)
#pragma unroll
                    for (int nf = 0; nf < 2; ++nf)
                        acc[mf][nf] = __builtin_amdgcn_mfma_f32_16x16x32_bf16(
                            af[mf], bfr[nf], acc[mf][nf], 0, 0, 0);
            }
            __syncthreads();
        }

        // epilogue: per-wave LDS transpose -> f32x4 NT stores
        float* ep = (float*)(smem + wid * 2304);
        const int crow_base = rb * 64 + wm * 32;
        const int ccol_base = cb * 64 + wn * 32;
#pragma unroll
        for (int mf = 0; mf < 2; ++mf) {
#pragma unroll
            for (int nf = 0; nf < 2; ++nf)
#pragma unroll
                for (int j = 0; j < 4; ++j)
                    ep[((lane >> 4) * 4 + j) * 36 + nf * 16 + (lane & 15)] = acc[mf][nf][j];
#pragma unroll
            for (int rep = 0; rep < 2; ++rep) {
                int row16 = rep * 8 + (lane >> 3);
                f32x4 v = *(const f32x4*)(ep + row16 * 36 + (lane & 7) * 4);
                float* dst = C + (size_t)(crow_base + mf * 16 + row16) * N_DIM
                             + ccol_base + (lane & 7) * 4;
                __builtin_nontemporal_store(v, (f32x4*)dst);
            }
        }
        __syncthreads();   // smem/sh_g safe for next queue iteration
    }
}

extern "C" void kernel_launch(void* const* d_in, const int* in_sizes, int n_in,
                              void* d_out, int out_size, void* d_ws, size_t ws_size,
                              hipStream_t stream) {
    const float* A = (const float*)d_in[0];
    const float* B = (const float*)d_in[1];
    float* C = (float*)d_out;

    // Workspace: [0,8MB) Btk [cb][kt]; [8MB,40MB) Abf; at +40MB:
    //   maskb 2048B | convCnt 32*u32 @+2048 | scanCnt 128*u32 @+2176 | queue @+2688
    char* Btk = (char*)d_ws;
    char* Abf = (char*)d_ws + (size_t)8 * 1024 * 1024;
    char* ctrl = (char*)d_ws + (size_t)40 * 1024 * 1024;
    uint8_t* maskb = (uint8_t*)ctrl;
    uint32_t* convCnt = (uint32_t*)(ctrl + 2048);
    uint32_t* scanCnt = (uint32_t*)(ctrl + 2176);
    uint32_t* queue   = (uint32_t*)(ctrl + 2688);

    hipMemsetAsync(ctrl, 0, 4096, stream);
    fused<<<1024, 256, 0, stream>>>(A, B, Btk, Abf, maskb, convCnt, scanCnt,
                                    queue, C);
}

// Round 23
// 878.219 us; speedup vs baseline: 1.0161x; 1.0161x over previous
//
#include <hip/hip_runtime.h>
#include <hip/hip_bf16.h>
#include <stdint.h>

// Problem constants (fixed by the reference).
#define M_DIM 8192
#define K_DIM 2048
#define N_DIM 2048

typedef __attribute__((ext_vector_type(8))) short bf16x8;
typedef __attribute__((ext_vector_type(4))) float f32x4;

// fp32 -> bf16 round-to-nearest-even (data has no NaNs).
__device__ __forceinline__ ushort f2bf(float f) {
    union { float f; uint32_t u; } v; v.f = f;
    uint32_t u = v.u;
    uint32_t r = u + 0x7fffu + ((u >> 16) & 1u);
    return (ushort)(r >> 16);
}

typedef const __attribute__((address_space(1))) uint32_t gu32;
typedef __attribute__((address_space(3))) uint32_t lu32;
__device__ __forceinline__ void load_lds16(const void* g, void* l) {
    __builtin_amdgcn_global_load_lds((gu32*)g, (lu32*)l, 16, 0, 0);
}

// Images (XOR-swizzled LDS format):
//   A: per tile (rb*32+kt), 8KB: byte(r,k2) = r*128 + (k2 ^ ((r&7)<<4))
//   B: per (cb,kt), 8KB panel at Btk + cb*256KB + kt*8KB  ([cb][kt])
//
// SINGLE kernel, 1024 blocks (all co-resident: empirically verified in R22
// at this exact LDS/launch_bounds config — required for deadlock freedom):
//   blocks [0,256):    4 conv units, then 2 scan units (rb 48..63 / 112..127)
//   blocks [256,1024): 2 scan units (rb 0..47 first / 64..111 second)
//   all blocks then consume gemm tiles from an rb-major atomic queue.
// R22 lesson: poll with ACQUIRE LOADS (concurrent), never atomic RMWs
// (they serialize at the memory controller -> 892us of spin).
__global__ __launch_bounds__(256, 4) void fused(const float* __restrict__ A,
                                                const float* __restrict__ B,
                                                char* __restrict__ Btk,
                                                char* __restrict__ Abf,
                                                uint8_t* __restrict__ maskb,
                                                uint32_t* __restrict__ convCnt,
                                                uint32_t* __restrict__ scanCnt,
                                                uint32_t* __restrict__ queue,
                                                float* __restrict__ C) {
    __shared__ __align__(16) char smem[16384];
    __shared__ int sh_g;
    const int b = blockIdx.x;
    const int t = threadIdx.x;

    // ================= producer: conv (blocks 0..255, 4 units each) =========
    if (b < 256) {
        ushort(*lds)[70] = (ushort(*)[70])smem;
#pragma unroll 1
        for (int j = 0; j < 4; ++j) {
            const int c = b + j * 256;        // conv unit 0..1023
            const int cbi = c & 31;
            const int kt = c >> 5;
            const int c0 = cbi * 64;
            const int r0 = kt * 64;
            const int r  = t >> 2;
            const int cs = (t & 3) << 2;
            __syncthreads();                  // smem reuse across units
#pragma unroll
            for (int i = 0; i < 4; ++i) {
                int cc = cs + i * 16;
                float4 v = *(const float4*)(B + (size_t)(r0 + r) * N_DIM + c0 + cc);
                lds[r][cc + 0] = f2bf(v.x);
                lds[r][cc + 1] = f2bf(v.y);
                lds[r][cc + 2] = f2bf(v.z);
                lds[r][cc + 3] = f2bf(v.w);
            }
            __syncthreads();
            const int ct = t >> 2;
            const int s  = (t & 3) * 16;
            uint4 tmpv[2];
            ushort* tmp = (ushort*)tmpv;
#pragma unroll
            for (int jj = 0; jj < 16; ++jj) tmp[jj] = lds[s + jj][ct];
            char* dst = Btk + (size_t)cbi * 262144 + (size_t)kt * 8192 + ct * 128;
            const int swn = (ct & 7) << 4;
            *(uint4*)(dst + ((s * 2)      ^ swn)) = tmpv[0];
            *(uint4*)(dst + ((s * 2 + 16) ^ swn)) = tmpv[1];
            __threadfence();                  // release this unit's writes
            __syncthreads();
            if (t == 0) atomicAdd(&convCnt[cbi], 1u);
        }
    }

    // ================= producer: scans (ALL blocks, 2 units each) ===========
    // Blocks 256..1023 take u 0..767 (rb 0..47) FIRST; conv blocks take
    // u 768..1023 (rb 48..63) after their convs. Round 2 adds 1024.
    {
        const int r  = t >> 2;
        const int cs = (t & 3) << 2;
        const int sw = (r & 7) << 4;
        const int u0 = (b + 768) & 1023;      // blocks 256.. -> u 0..767
#pragma unroll 1
        for (int k = 0; k < 2; ++k) {
            const int u = u0 + k * 1024;      // 0..2047
            const int rb = u >> 4;
            const int part = u & 15;
            const int kt0 = part * 2;
            const float* base = A + (size_t)(rb * 64 + r) * K_DIM + kt0 * 64 + cs;
            uint32_t bits = 0;
            float4 cur[4], nxt[4];
#pragma unroll
            for (int i = 0; i < 4; ++i) cur[i] = *(const float4*)(base + i * 16);
#pragma unroll
            for (int it = 0; it < 2; ++it) {
                if (it < 1) {
#pragma unroll
                    for (int i = 0; i < 4; ++i)
                        nxt[i] = *(const float4*)(base + 64 + i * 16);
                }
                bool nz = false;
#pragma unroll
                for (int i = 0; i < 4; ++i)
                    nz = nz || (cur[i].x != 0.f) || (cur[i].y != 0.f) ||
                               (cur[i].z != 0.f) || (cur[i].w != 0.f);
                int anynz = __syncthreads_or((int)nz);
                if (anynz) {
                    bits |= 1u << it;
                    char* dst = Abf + (size_t)(rb * 32 + kt0 + it) * 8192 + r * 128;
#pragma unroll
                    for (int i = 0; i < 4; ++i) {
                        uint32_t lo = (uint32_t)f2bf(cur[i].x) | ((uint32_t)f2bf(cur[i].y) << 16);
                        uint32_t hi = (uint32_t)f2bf(cur[i].z) | ((uint32_t)f2bf(cur[i].w) << 16);
                        *(uint2*)(dst + ((cs * 2 + i * 32) ^ sw)) = make_uint2(lo, hi);
                    }
                }
#pragma unroll
                for (int i = 0; i < 4; ++i) cur[i] = nxt[i];
            }
            if (t == 0) maskb[u] = (uint8_t)bits;   // u == rb*16 + part
            __threadfence();                  // release Abf + mask
            __syncthreads();
            if (t == 0) atomicAdd(&scanCnt[rb], 1u);
        }
    }

    // ================= consumer: gemm via atomic work queue =================
    char* sA = smem;
    char* sB = smem + 8192;
    const int lane = t & 63;
    const int wid = t >> 6;
    const int wm = wid >> 1;
    const int wn = wid & 1;

    for (;;) {
        if (t == 0) sh_g = (int)atomicAdd(queue, 1u);
        __syncthreads();
        const int g = sh_g;
        if (g >= 4096) break;
        const int rb = g >> 5;               // rb-ascending: matches scan order
        const int cb = g & 31;

        if (t == 0) {
            // R22 fix: ACQUIRE LOAD polling (concurrent), not atomic RMW.
            while (__hip_atomic_load(&convCnt[cb], __ATOMIC_ACQUIRE,
                                     __HIP_MEMORY_SCOPE_AGENT) < 32u)
                __builtin_amdgcn_s_sleep(16);
            while (__hip_atomic_load(&scanCnt[rb], __ATOMIC_ACQUIRE,
                                     __HIP_MEMORY_SCOPE_AGENT) < 16u)
                __builtin_amdgcn_s_sleep(16);
        }
        __syncthreads();
        __threadfence();                      // acquire producer data (all lanes)

        uint32_t m = 0;
        const uint8_t* mbp = maskb + rb * 16;
#pragma unroll
        for (int u2 = 0; u2 < 16; ++u2) m |= ((uint32_t)mbp[u2]) << (2 * u2);

        f32x4 acc[2][2];
#pragma unroll
        for (int i = 0; i < 2; ++i)
#pragma unroll
            for (int j = 0; j < 2; ++j) acc[i][j] = (f32x4){0.f, 0.f, 0.f, 0.f};

        const char* bcol = Btk + (size_t)cb * 262144;

        while (m) {
            const int kt = __ffs((int)m) - 1;
            m &= (m - 1);
            {
                const char* bt = bcol + (size_t)kt * 8192;
#pragma unroll
                for (int i = 0; i < 2; ++i) {
                    const int ch = wid * 2 + i;
                    load_lds16(bt + ch * 1024 + lane * 16, sB + ch * 1024);
                }
                const char* at = Abf + (size_t)(rb * 32 + kt) * 8192;
#pragma unroll
                for (int i = 0; i < 2; ++i) {
                    const int ch = wid * 2 + i;
                    load_lds16(at + ch * 1024 + lane * 16, sA + ch * 1024);
                }
            }
            __syncthreads();

#pragma unroll
            for (int ks = 0; ks < 2; ++ks) {
                bf16x8 af[2], bfr[2];
#pragma unroll
                for (int mf = 0; mf < 2; ++mf) {
                    int row = wm * 32 + mf * 16 + (lane & 15);
                    int byte = row * 128 + (ks * 32 + (lane >> 4) * 8) * 2;
                    byte ^= ((row & 7) << 4);
                    af[mf] = *(const bf16x8*)(sA + byte);
                }
#pragma unroll
                for (int nf = 0; nf < 2; ++nf) {
                    int row = wn * 32 + nf * 16 + (lane & 15);
                    int byte = row * 128 + (ks * 32 + (lane >> 4) * 8) * 2;
                    byte ^= ((row & 7) << 4);
                    bfr[nf] = *(const bf16x8*)(sB + byte);
                }
#pragma unroll
                for (int mf = 0; mf < 2; ++mf)
#pragma unroll
                    for (int nf = 0; nf < 2; ++nf)
                        acc[mf][nf] = __builtin_amdgcn_mfma_f32_16x16x32_bf16(
                            af[mf], bfr[nf], acc[mf][nf], 0, 0, 0);
            }
            __syncthreads();
        }

        // epilogue: per-wave LDS transpose -> f32x4 NT stores
        float* ep = (float*)(smem + wid * 2304);
        const int crow_base = rb * 64 + wm * 32;
        const int ccol_base = cb * 64 + wn * 32;
#pragma unroll
        for (int mf = 0; mf < 2; ++mf) {
#pragma unroll
            for (int nf = 0; nf < 2; ++nf)
#pragma unroll
                for (int j = 0; j < 4; ++j)
                    ep[((lane >> 4) * 4 + j) * 36 + nf * 16 + (lane & 15)] = acc[mf][nf][j];
#pragma unroll
            for (int rep = 0; rep < 2; ++rep) {
                int row16 = rep * 8 + (lane >> 3);
                f32x4 v = *(const f32x4*)(ep + row16 * 36 + (lane & 7) * 4);
                float* dst = C + (size_t)(crow_base + mf * 16 + row16) * N_DIM
                             + ccol_base + (lane & 7) * 4;
                __builtin_nontemporal_store(v, (f32x4*)dst);
            }
        }
        __syncthreads();   // smem/sh_g safe for next queue iteration
    }
}

extern "C" void kernel_launch(void* const* d_in, const int* in_sizes, int n_in,
                              void* d_out, int out_size, void* d_ws, size_t ws_size,
                              hipStream_t stream) {
    const float* A = (const float*)d_in[0];
    const float* B = (const float*)d_in[1];
    float* C = (float*)d_out;

    // Workspace: [0,8MB) Btk [cb][kt]; [8MB,40MB) Abf; at +40MB:
    //   maskb 2048B | convCnt 32*u32 @+2048 | scanCnt 128*u32 @+2176 | queue @+2688
    char* Btk = (char*)d_ws;
    char* Abf = (char*)d_ws + (size_t)8 * 1024 * 1024;
    char* ctrl = (char*)d_ws + (size_t)40 * 1024 * 1024;
    uint8_t* maskb = (uint8_t*)ctrl;
    uint32_t* convCnt = (uint32_t*)(ctrl + 2048);
    uint32_t* scanCnt = (uint32_t*)(ctrl + 2176);
    uint32_t* queue   = (uint32_t*)(ctrl + 2688);

    hipMemsetAsync(ctrl, 0, 4096, stream);
    fused<<<1024, 256, 0, stream>>>(A, B, Btk, Abf, maskb, convCnt, scanCnt,
                                    queue, C);
}

// Round 24
// 98.798 us; speedup vs baseline: 9.0322x; 8.8891x over previous
//
#include <hip/hip_runtime.h>
#include <hip/hip_bf16.h>
#include <stdint.h>

// Problem constants (fixed by the reference).
#define M_DIM 8192
#define K_DIM 2048
#define N_DIM 2048

typedef __attribute__((ext_vector_type(8))) short bf16x8;
typedef __attribute__((ext_vector_type(4))) float f32x4;

// fp32 -> bf16 round-to-nearest-even (data has no NaNs).
__device__ __forceinline__ ushort f2bf(float f) {
    union { float f; uint32_t u; } v; v.f = f;
    uint32_t u = v.u;
    uint32_t r = u + 0x7fffu + ((u >> 16) & 1u);
    return (ushort)(r >> 16);
}

typedef const __attribute__((address_space(1))) uint32_t gu32;
typedef __attribute__((address_space(3))) uint32_t lu32;
__device__ __forceinline__ void load_lds16(const void* g, void* l) {
    // 16B per lane, dest = wave-uniform LDS base + lane*16 (HW rule).
    __builtin_amdgcn_global_load_lds((gu32*)g, (lu32*)l, 16, 0, 0);
}

// Workspace images are byte-for-byte LDS images (XOR-swizzled):
//   A image: per tile (rb*32+kt), 8KB: byte(r,k2) = r*128 + (k2 ^ ((r&7)<<4))
//   B image: per (cb,kt), 8KB panel at Btk + cb*256KB + kt*8KB ([cb][kt]).
//
// prep: byte-identical to R21 (measured ~15 us, ~= traffic floor).
__global__ __launch_bounds__(256) void prep(const float* __restrict__ A,
                                            const float* __restrict__ B,
                                            char* __restrict__ Btk,
                                            char* __restrict__ Abf,
                                            uint8_t* __restrict__ maskb) {
    __shared__ __align__(16) ushort lds[64][70];
    const int b = blockIdx.x;
    const int t = threadIdx.x;

    if (b < 512) {
        // ---- scan + pack: 8 k-tiles of one row-block quarter ----
        const int rb = b >> 2;
        const int seg = b & 3;
        const int r  = t >> 2;            // row in tile 0..63
        const int cs = (t & 3) << 2;      // float col base {0,4,8,12}; +i*16
        const float* base = A + (size_t)(rb * 64 + r) * K_DIM + seg * 512 + cs;
        const int sw = (r & 7) << 4;
        uint32_t outb = 0;
        float4 cur[4], nxt[4];
#pragma unroll
        for (int i = 0; i < 4; ++i) cur[i] = *(const float4*)(base + i * 16);
#pragma unroll
        for (int it = 0; it < 8; ++it) {
            if (it < 7) {
#pragma unroll
                for (int i = 0; i < 4; ++i) nxt[i] = *(const float4*)(base + (it + 1) * 64 + i * 16);
            }
            bool nz = false;
#pragma unroll
            for (int i = 0; i < 4; ++i)
                nz = nz || (cur[i].x != 0.f) || (cur[i].y != 0.f) ||
                           (cur[i].z != 0.f) || (cur[i].w != 0.f);
            int anynz = __syncthreads_or((int)nz);
            if (anynz) {
                outb |= 1u << it;
                char* dst = Abf + (size_t)(rb * 32 + seg * 8 + it) * 8192 + r * 128;
#pragma unroll
                for (int i = 0; i < 4; ++i) {
                    uint32_t lo = (uint32_t)f2bf(cur[i].x) | ((uint32_t)f2bf(cur[i].y) << 16);
                    uint32_t hi = (uint32_t)f2bf(cur[i].z) | ((uint32_t)f2bf(cur[i].w) << 16);
                    *(uint2*)(dst + ((cs * 2 + i * 32) ^ sw)) = make_uint2(lo, hi);
                }
            }
#pragma unroll
            for (int i = 0; i < 4; ++i) cur[i] = nxt[i];
        }
        if (t == 0) maskb[rb * 4 + seg] = (uint8_t)outb;
    } else {
        // ---- conv: one 64x64 tile of B -> swizzled [cb][kt] image ----
        const int c = b - 512;
        const int cbi = c & 31;           // 64-wide column block 0..31
        const int c0 = cbi * 64;          // N offset
        const int kt = c >> 5;            // 0..31
        const int r0 = kt * 64;           // K offset
        const int r  = t >> 2;
        const int cs = (t & 3) << 2;
#pragma unroll
        for (int i = 0; i < 4; ++i) {
            int cc = cs + i * 16;
            float4 v = *(const float4*)(B + (size_t)(r0 + r) * N_DIM + c0 + cc);
            lds[r][cc + 0] = f2bf(v.x);
            lds[r][cc + 1] = f2bf(v.y);
            lds[r][cc + 2] = f2bf(v.z);
            lds[r][cc + 3] = f2bf(v.w);
        }
        __syncthreads();
        const int ct = t >> 2;            // n within tile, 0..63
        const int s  = (t & 3) * 16;      // k segment base
        uint4 tmpv[2];
        ushort* tmp = (ushort*)tmpv;
#pragma unroll
        for (int j = 0; j < 16; ++j) tmp[j] = lds[s + j][ct];
        char* dst = Btk + (size_t)cbi * 262144 + (size_t)kt * 8192 + ct * 128;
        const int swn = (ct & 7) << 4;
        *(uint4*)(dst + ((s * 2)      ^ swn)) = tmpv[0];
        *(uint4*)(dst + ((s * 2 + 16) ^ swn)) = tmpv[1];
    }
}

// Block-sparse GEMM: R21 structure (64x64 tile, single-buffered 16KB LDS,
// VGPR cap (256,8), 2D XCD partition, NT stores — best 37.5us) with ONE
// change: per-XCD atomic WORK QUEUES replace the static block->tile map.
// 2048 persistent blocks (8/CU, R21-verified) pull tiles until empty —
// collapses the Poisson(3.2)-nnz straggler tail (~3-4us of CU idle).
// Queue is pure load-balance: prep fully completed before dispatch, no
// fences/polling needed (R22/R23's pathology was the producer/consumer
// spin, not the queue).
__global__ __launch_bounds__(256, 8) void gemm_sparse(const char* __restrict__ Abf,
                                                      const char* __restrict__ Btk,
                                                      const uint32_t* __restrict__ mask,
                                                      uint32_t* __restrict__ queues,
                                                      float* __restrict__ C) {
    // [sA 8K][sB 8K] = 16KB; epilogue reuses [0, 9216) as 4 x 2304B wave regions
    __shared__ __align__(16) char smem[16384];
    __shared__ int sh_g;
    char* sA = smem;
    char* sB = smem + 8192;

    const int xcd = blockIdx.x & 7;            // round-robin wg->XCD assumption
    uint32_t* myq = queues + xcd;
    const int tid = threadIdx.x;
    const int lane = tid & 63;
    const int wid = tid >> 6;
    const int wm = wid >> 1;      // 0..1
    const int wn = wid & 1;       // 0..1

    for (;;) {
        if (tid == 0) sh_g = (int)atomicAdd(myq, 1u);
        __syncthreads();
        const int g = sh_g;
        if (g >= 512) break;                   // this XCD's 512 tiles done

        // XCD x owns rb-half (x&1) x cb-group (x>>1); consecutive g share rb.
        const int cb = (xcd >> 1) * 8 + (g & 7);    // 0..31
        const int rb = (xcd & 1) * 64 + (g >> 3);   // 0..127

        f32x4 acc[2][2];
#pragma unroll
        for (int i = 0; i < 2; ++i)
#pragma unroll
            for (int j = 0; j < 2; ++j) acc[i][j] = (f32x4){0.f, 0.f, 0.f, 0.f};

        uint32_t m = mask[rb];
        const char* bcol = Btk + (size_t)cb * 262144;

        while (m) {
            const int kt = __ffs((int)m) - 1;
            m &= (m - 1);

            // stage B panel (8KB) + A tile (8KB): 4 linear gload_lds per thread
            {
                const char* bt = bcol + (size_t)kt * 8192;
#pragma unroll
                for (int i = 0; i < 2; ++i) {
                    const int ch = wid * 2 + i;             // 0..7, 1KB each
                    load_lds16(bt + ch * 1024 + lane * 16, sB + ch * 1024);
                }
                const char* at = Abf + (size_t)(rb * 32 + kt) * 8192;
#pragma unroll
                for (int i = 0; i < 2; ++i) {
                    const int ch = wid * 2 + i;
                    load_lds16(at + ch * 1024 + lane * 16, sA + ch * 1024);
                }
            }
            __syncthreads();    // staged data visible to all waves

#pragma unroll
            for (int ks = 0; ks < 2; ++ks) {
                bf16x8 af[2], bfr[2];
#pragma unroll
                for (int mf = 0; mf < 2; ++mf) {
                    int row = wm * 32 + mf * 16 + (lane & 15);
                    int byte = row * 128 + (ks * 32 + (lane >> 4) * 8) * 2;
                    byte ^= ((row & 7) << 4);
                    af[mf] = *(const bf16x8*)(sA + byte);
                }
#pragma unroll
                for (int nf = 0; nf < 2; ++nf) {
                    int row = wn * 32 + nf * 16 + (lane & 15);
                    int byte = row * 128 + (ks * 32 + (lane >> 4) * 8) * 2;
                    byte ^= ((row & 7) << 4);
                    bfr[nf] = *(const bf16x8*)(sB + byte);
                }
#pragma unroll
                for (int mf = 0; mf < 2; ++mf)
#pragma unroll
                    for (int nf = 0; nf < 2; ++nf)
                        acc[mf][nf] = __builtin_amdgcn_mfma_f32_16x16x32_bf16(
                            af[mf], bfr[nf], acc[mf][nf], 0, 0, 0);
            }
            __syncthreads();    // buffer consumed -> safe to restage
        }

        // ---- epilogue: per-wave compact 2-pass LDS transpose -> NT stores ----
        // MFMA C/D layout: col=lane&15, row=(lane>>4)*4+reg. Wave-private
        // 16x36-float region (2304B), reused across mf halves (DS in-order).
        float* ep = (float*)(smem + wid * 2304);
        const int crow_base = rb * 64 + wm * 32;
        const int ccol_base = cb * 64 + wn * 32;
#pragma unroll
        for (int mf = 0; mf < 2; ++mf) {
#pragma unroll
            for (int nf = 0; nf < 2; ++nf)
#pragma unroll
                for (int j = 0; j < 4; ++j)
                    ep[((lane >> 4) * 4 + j) * 36 + nf * 16 + (lane & 15)] = acc[mf][nf][j];
#pragma unroll
            for (int rep = 0; rep < 2; ++rep) {
                int row16 = rep * 8 + (lane >> 3);
                f32x4 v = *(const f32x4*)(ep + row16 * 36 + (lane & 7) * 4);
                float* dst = C + (size_t)(crow_base + mf * 16 + row16) * N_DIM
                             + ccol_base + (lane & 7) * 4;
                __builtin_nontemporal_store(v, (f32x4*)dst);
            }
        }
        __syncthreads();   // smem + sh_g safe before next queue pull
    }
}

extern "C" void kernel_launch(void* const* d_in, const int* in_sizes, int n_in,
                              void* d_out, int out_size, void* d_ws, size_t ws_size,
                              hipStream_t stream) {
    const float* A = (const float*)d_in[0];
    const float* B = (const float*)d_in[1];
    float* C = (float*)d_out;

    // Workspace: [0,8MB) Btk [cb][kt]; [8MB,40MB) Abf; at +40MB:
    //   mask 512B (u32 x 128) | queues 8 x u32 @ +1024
    char* Btk = (char*)d_ws;
    char* Abf = (char*)d_ws + (size_t)8 * 1024 * 1024;
    char* ctrl = (char*)d_ws + (size_t)40 * 1024 * 1024;
    uint8_t* maskb = (uint8_t*)ctrl;
    uint32_t* queues = (uint32_t*)(ctrl + 1024);

    hipMemsetAsync(queues, 0, 32, stream);
    prep<<<1536, 256, 0, stream>>>(A, B, Btk, Abf, maskb);
    gemm_sparse<<<2048, 256, 0, stream>>>(Abf, Btk, (const uint32_t*)maskb,
                                          queues, C);
}

// Round 25
// 37.381 us; speedup vs baseline: 23.8721x; 2.6430x over previous
//
#include <hip/hip_runtime.h>
#include <hip/hip_bf16.h>
#include <stdint.h>

// Problem constants (fixed by the reference).
#define M_DIM 8192
#define K_DIM 2048
#define N_DIM 2048

typedef __attribute__((ext_vector_type(8))) short bf16x8;
typedef __attribute__((ext_vector_type(4))) float f32x4;

// fp32 -> bf16 round-to-nearest-even (data has no NaNs).
__device__ __forceinline__ ushort f2bf(float f) {
    union { float f; uint32_t u; } v; v.f = f;
    uint32_t u = v.u;
    uint32_t r = u + 0x7fffu + ((u >> 16) & 1u);
    return (ushort)(r >> 16);
}

typedef const __attribute__((address_space(1))) uint32_t gu32;
typedef __attribute__((address_space(3))) uint32_t lu32;
__device__ __forceinline__ void load_lds16(const void* g, void* l) {
    // 16B per lane, dest = wave-uniform LDS base + lane*16 (HW rule).
    __builtin_amdgcn_global_load_lds((gu32*)g, (lu32*)l, 16, 0, 0);
}

// Workspace images are byte-for-byte LDS images (XOR-swizzled):
//   A image: per tile (rb*32+kt), 8KB: byte(r,k2) = r*128 + (k2 ^ ((r&7)<<4))
//   B image: per (cb,kt), 8KB panel at Btk + cb*256KB + kt*8KB ([cb][kt]).
//
// prep: R9 structure (measured ~15 us ≈ its 14.5 us HBM traffic floor).
__global__ __launch_bounds__(256) void prep(const float* __restrict__ A,
                                            const float* __restrict__ B,
                                            char* __restrict__ Btk,
                                            char* __restrict__ Abf,
                                            uint8_t* __restrict__ maskb) {
    __shared__ __align__(16) ushort lds[64][70];
    const int b = blockIdx.x;
    const int t = threadIdx.x;

    if (b < 512) {
        // ---- scan + pack: 8 k-tiles of one row-block quarter ----
        const int rb = b >> 2;
        const int seg = b & 3;
        const int r  = t >> 2;            // row in tile 0..63
        const int cs = (t & 3) << 2;      // float col base {0,4,8,12}; +i*16
        const float* base = A + (size_t)(rb * 64 + r) * K_DIM + seg * 512 + cs;
        const int sw = (r & 7) << 4;
        uint32_t outb = 0;
        float4 cur[4], nxt[4];
#pragma unroll
        for (int i = 0; i < 4; ++i) cur[i] = *(const float4*)(base + i * 16);
#pragma unroll
        for (int it = 0; it < 8; ++it) {
            if (it < 7) {
#pragma unroll
                for (int i = 0; i < 4; ++i) nxt[i] = *(const float4*)(base + (it + 1) * 64 + i * 16);
            }
            bool nz = false;
#pragma unroll
            for (int i = 0; i < 4; ++i)
                nz = nz || (cur[i].x != 0.f) || (cur[i].y != 0.f) ||
                           (cur[i].z != 0.f) || (cur[i].w != 0.f);
            int anynz = __syncthreads_or((int)nz);
            if (anynz) {
                outb |= 1u << it;
                char* dst = Abf + (size_t)(rb * 32 + seg * 8 + it) * 8192 + r * 128;
#pragma unroll
                for (int i = 0; i < 4; ++i) {
                    uint32_t lo = (uint32_t)f2bf(cur[i].x) | ((uint32_t)f2bf(cur[i].y) << 16);
                    uint32_t hi = (uint32_t)f2bf(cur[i].z) | ((uint32_t)f2bf(cur[i].w) << 16);
                    *(uint2*)(dst + ((cs * 2 + i * 32) ^ sw)) = make_uint2(lo, hi);
                }
            }
#pragma unroll
            for (int i = 0; i < 4; ++i) cur[i] = nxt[i];
        }
        if (t == 0) maskb[rb * 4 + seg] = (uint8_t)outb;
    } else {
        // ---- conv: one 64x64 tile of B -> swizzled [cb][kt] image ----
        const int c = b - 512;
        const int cbi = c & 31;           // 64-wide column block 0..31
        const int c0 = cbi * 64;          // N offset
        const int kt = c >> 5;            // 0..31
        const int r0 = kt * 64;           // K offset
        const int r  = t >> 2;
        const int cs = (t & 3) << 2;
#pragma unroll
        for (int i = 0; i < 4; ++i) {
            int cc = cs + i * 16;
            float4 v = *(const float4*)(B + (size_t)(r0 + r) * N_DIM + c0 + cc);
            lds[r][cc + 0] = f2bf(v.x);
            lds[r][cc + 1] = f2bf(v.y);
            lds[r][cc + 2] = f2bf(v.z);
            lds[r][cc + 3] = f2bf(v.w);
        }
        __syncthreads();
        const int ct = t >> 2;            // n within tile, 0..63
        const int s  = (t & 3) * 16;      // k segment base
        uint4 tmpv[2];
        ushort* tmp = (ushort*)tmpv;
#pragma unroll
        for (int j = 0; j < 16; ++j) tmp[j] = lds[s + j][ct];
        char* dst = Btk + (size_t)cbi * 262144 + (size_t)kt * 8192 + ct * 128;
        const int swn = (ct & 7) << 4;
        *(uint4*)(dst + ((s * 2)      ^ swn)) = tmpv[0];
        *(uint4*)(dst + ((s * 2 + 16) ^ swn)) = tmpv[1];
    }
}

// Block-sparse GEMM (R21 — best measured 37.5us): 64x64 tile, single-buffered
// 16KB LDS, VGPR cap (256,8) -> 8 blocks/CU, static 2D XCD partition (per-XCD
// L2 set = A 1.64MB + B 2MB < 4MB), NT C-stores. 24 rounds of A/Bs: dbuf,
// counted-vmcnt, tile shapes, no-LDS fragment-direct, cached stores, B
// layouts, work queues, and producer/consumer fusion all measured neutral or
// worse — this static configuration is the plateau of the decomposition.
__global__ __launch_bounds__(256, 8) void gemm_sparse(const char* __restrict__ Abf,
                                                      const char* __restrict__ Btk,
                                                      const uint32_t* __restrict__ mask,
                                                      float* __restrict__ C) {
    // [sA 8K][sB 8K] = 16KB; epilogue reuses [0, 9216) as 4 x 2304B wave regions
    __shared__ __align__(16) char smem[16384];
    char* sA = smem;
    char* sB = smem + 8192;

    const int orig = blockIdx.x;
    const int xcd = orig & 7;                  // round-robin wg->XCD assumption
    const int i0 = orig >> 3;                  // 0..511
    const int cb = (xcd >> 1) * 8 + (i0 & 7);  // 0..31: 8 cols per XCD-pair (B 2MB)
    const int rb = (xcd & 1) * 64 + (i0 >> 3); // 0..127: rb-half per XCD parity (A 1.64MB)
    const int tid = threadIdx.x;
    const int lane = tid & 63;
    const int wid = tid >> 6;
    const int wm = wid >> 1;      // 0..1
    const int wn = wid & 1;       // 0..1

    f32x4 acc[2][2];
#pragma unroll
    for (int i = 0; i < 2; ++i)
#pragma unroll
        for (int j = 0; j < 2; ++j) acc[i][j] = (f32x4){0.f, 0.f, 0.f, 0.f};

    uint32_t m = mask[rb];
    const char* bcol = Btk + (size_t)cb * 262144;   // contiguous B range

    while (m) {
        const int kt = __ffs((int)m) - 1;
        m &= (m - 1);

        // stage B panel (8KB) + A tile (8KB): 4 linear gload_lds per thread
        {
            const char* bt = bcol + (size_t)kt * 8192;
#pragma unroll
            for (int i = 0; i < 2; ++i) {
                const int ch = wid * 2 + i;                 // 0..7, 1KB each
                load_lds16(bt + ch * 1024 + lane * 16, sB + ch * 1024);
            }
            const char* at = Abf + (size_t)(rb * 32 + kt) * 8192;
#pragma unroll
            for (int i = 0; i < 2; ++i) {
                const int ch = wid * 2 + i;
                load_lds16(at + ch * 1024 + lane * 16, sA + ch * 1024);
            }
        }
        __syncthreads();    // drains vmcnt -> staged data visible to all waves

#pragma unroll
        for (int ks = 0; ks < 2; ++ks) {
            bf16x8 af[2], bfr[2];
#pragma unroll
            for (int mf = 0; mf < 2; ++mf) {
                int row = wm * 32 + mf * 16 + (lane & 15);
                int byte = row * 128 + (ks * 32 + (lane >> 4) * 8) * 2;
                byte ^= ((row & 7) << 4);
                af[mf] = *(const bf16x8*)(sA + byte);
            }
#pragma unroll
            for (int nf = 0; nf < 2; ++nf) {
                int row = wn * 32 + nf * 16 + (lane & 15);
                int byte = row * 128 + (ks * 32 + (lane >> 4) * 8) * 2;
                byte ^= ((row & 7) << 4);
                bfr[nf] = *(const bf16x8*)(sB + byte);
            }
#pragma unroll
            for (int mf = 0; mf < 2; ++mf)
#pragma unroll
                for (int nf = 0; nf < 2; ++nf)
                    acc[mf][nf] = __builtin_amdgcn_mfma_f32_16x16x32_bf16(
                        af[mf], bfr[nf], acc[mf][nf], 0, 0, 0);
        }
        __syncthreads();    // buffer consumed -> safe to restage
    }

    // ---- epilogue: per-wave compact 2-pass LDS transpose -> f32x4 NT stores ----
    // MFMA C/D layout: col=lane&15, row=(lane>>4)*4+reg. Wave-private 16x36-float
    // region (2304B) reused across the two mf halves (DS pipe in-order per wave).
    float* ep = (float*)(smem + wid * 2304);
    const int crow_base = rb * 64 + wm * 32;
    const int ccol_base = cb * 64 + wn * 32;
#pragma unroll
    for (int mf = 0; mf < 2; ++mf) {
#pragma unroll
        for (int nf = 0; nf < 2; ++nf)
#pragma unroll
            for (int j = 0; j < 4; ++j)
                ep[((lane >> 4) * 4 + j) * 36 + nf * 16 + (lane & 15)] = acc[mf][nf][j];
#pragma unroll
        for (int rep = 0; rep < 2; ++rep) {
            int row16 = rep * 8 + (lane >> 3);
            f32x4 v = *(const f32x4*)(ep + row16 * 36 + (lane & 7) * 4);
            float* dst = C + (size_t)(crow_base + mf * 16 + row16) * N_DIM
                         + ccol_base + (lane & 7) * 4;
            __builtin_nontemporal_store(v, (f32x4*)dst);
        }
    }
}

extern "C" void kernel_launch(void* const* d_in, const int* in_sizes, int n_in,
                              void* d_out, int out_size, void* d_ws, size_t ws_size,
                              hipStream_t stream) {
    const float* A = (const float*)d_in[0];
    const float* B = (const float*)d_in[1];
    float* C = (float*)d_out;

    // Workspace: [0,8MB) Btk [cb][kt]; [8MB,40MB) Abf; [40MB,+512) mask
    char* Btk = (char*)d_ws;
    char* Abf = (char*)d_ws + (size_t)8 * 1024 * 1024;
    uint8_t* maskb = (uint8_t*)((char*)d_ws + (size_t)40 * 1024 * 1024);

    prep<<<1536, 256, 0, stream>>>(A, B, Btk, Abf, maskb);
    gemm_sparse<<<(M_DIM / 64) * (N_DIM / 64), 256, 0, stream>>>(
        Abf, Btk, (const uint32_t*)maskb, C);
}